// Round 2
// baseline (183.104 us; speedup 1.0000x reference)
//
#include <hip/hip_runtime.h>
#include <math.h>

// Capsule dynamic routing, MI355X. Round 2: ALL-FP32 I/O (reference dtype),
// u_hat algebraically eliminated (V/G factorization):
//   logits[b,j,n] = u[b,n,:] . V[b,j,:],  V[b,j,k] = sum_d W[k,jd]*o[b,j,d]
//   o[b,j,d]      = sum_k G[b,j,k]*W[k,jd], G[b,j,k] = sum_n c[b,j,n]*u[b,n,k]
// iter0: c uniform 0.1 -> o0 = 0.1*(colsum u)@W.

#define BATCH 64
#define NN    2048
#define KD    128
#define JCAP  10
#define DCAP  16
#define JDIM  160
#define EPSQ  1e-7f

// ---- K1: S[b][k] = sum_n u[b][n][k] ------------------------------------
__global__ __launch_bounds__(256) void k_colsum(const float* __restrict__ u,
                                                float* __restrict__ S) {
  const int b    = blockIdx.y;
  const int tile = blockIdx.x;            // 8 tiles of 256 rows
  const int t    = threadIdx.x;
  const int k4   = (t & 31) * 4;          // 4 consecutive k per thread
  const int rg   = t >> 5;                // 8 row groups of 32 rows
  const float* p = u + ((size_t)(b * NN) + tile * 256 + rg * 32) * KD + k4;
  float a0 = 0.f, a1 = 0.f, a2 = 0.f, a3 = 0.f;
#pragma unroll 4
  for (int r = 0; r < 32; ++r) {
    float4 w = *(const float4*)(p + (size_t)r * KD);
    a0 += w.x; a1 += w.y; a2 += w.z; a3 += w.w;
  }
  atomicAdd(&S[b * KD + k4 + 0], a0);
  atomicAdd(&S[b * KD + k4 + 1], a1);
  atomicAdd(&S[b * KD + k4 + 2], a2);
  atomicAdd(&S[b * KD + k4 + 3], a3);
}

// ---- K2: o[b,j,d] = scale * sum_k Gin*W ; V[b,j,k] = sum_d W[k,jd]*o ---
__global__ __launch_bounds__(256) void k_makeV(const float* __restrict__ Gin,
                                               const float* __restrict__ W,
                                               float* __restrict__ V,
                                               int fromS, float scale) {
  const int b = blockIdx.x;
  const int t = threadIdx.x;
  __shared__ float o_s[JDIM];
  if (t < JDIM) {
    const int j = t >> 4;
    const float* g = fromS ? (Gin + b * KD) : (Gin + (size_t)(b * JCAP + j) * KD);
    float acc = 0.f;
#pragma unroll 4
    for (int k = 0; k < KD; ++k) acc += g[k] * W[k * JDIM + t];
    o_s[t] = acc * scale;
  }
  __syncthreads();
  const int k = t & 127, gg = t >> 7;
#pragma unroll
  for (int i = 0; i < 5; ++i) {
    const int j = gg * 5 + i;
    const float* wp = W + k * JDIM + j * DCAP;
    float acc = 0.f;
#pragma unroll
    for (int d = 0; d < DCAP; ++d) acc += wp[d] * o_s[j * DCAP + d];
    V[(size_t)(b * JCAP + j) * KD + k] = acc;
  }
}

// ---- K3: one routing pass: logits -> softmax_j -> G += c^T u -----------
__global__ __launch_bounds__(256) void k_route(const float* __restrict__ u,
                                               const float* __restrict__ V,
                                               float* __restrict__ G) {
  const int b    = blockIdx.y;
  const int tile = blockIdx.x;            // 8 tiles x 256 rows
  const int t    = threadIdx.x;
  const int r0   = tile * 256;
  __shared__ float Cs[JCAP][260];         // c transposed [j][row], padded
  __shared__ float Gp[4][JCAP][KD];       // per-wave G partials (20 KB)

  // phase 1: thread = row; 10 logits + softmax fully in registers
  {
    const float* up = u + (size_t)(b * NN + r0 + t) * KD;
    const float* vb = V + (size_t)(b * JCAP) * KD;   // block-uniform -> s_load
    float acc[JCAP];
#pragma unroll
    for (int j = 0; j < JCAP; ++j) acc[j] = 0.f;
    for (int kc = 0; kc < KD; kc += 8) {
      float4 xa = *(const float4*)(up + kc);
      float4 xb = *(const float4*)(up + kc + 4);
#pragma unroll
      for (int j = 0; j < JCAP; ++j) {
        const float4 v0 = *(const float4*)(vb + j * KD + kc);
        const float4 v1 = *(const float4*)(vb + j * KD + kc + 4);
        acc[j] += xa.x * v0.x + xa.y * v0.y + xa.z * v0.z + xa.w * v0.w
                + xb.x * v1.x + xb.y * v1.y + xb.z * v1.z + xb.w * v1.w;
      }
    }
    float m = acc[0];
#pragma unroll
    for (int j = 1; j < JCAP; ++j) m = fmaxf(m, acc[j]);
    float s = 0.f;
#pragma unroll
    for (int j = 0; j < JCAP; ++j) { acc[j] = __expf(acc[j] - m); s += acc[j]; }
    const float inv = 1.f / s;
#pragma unroll
    for (int j = 0; j < JCAP; ++j) Cs[j][t] = acc[j] * inv;
  }
  __syncthreads();

  // phase 2: wave covers 64 rows, lane covers k = 2*lane, 2*lane+1
  {
    const int wave = t >> 6, lane = t & 63;
    const int rw = wave * 64;
    float g0[JCAP], g1[JCAP];
#pragma unroll
    for (int j = 0; j < JCAP; ++j) { g0[j] = 0.f; g1[j] = 0.f; }
    const float* ub = u + (size_t)(b * NN + r0 + rw) * KD + 2 * lane;
    for (int rc = 0; rc < 64; rc += 4) {
      float ua[4], ubv[4];
#pragma unroll
      for (int q = 0; q < 4; ++q) {
        float2 w = *(const float2*)(ub + (size_t)(rc + q) * KD);
        ua[q] = w.x; ubv[q] = w.y;
      }
#pragma unroll
      for (int j = 0; j < JCAP; ++j) {
        float4 c4 = *(const float4*)&Cs[j][rw + rc];   // broadcast b128
        g0[j] += c4.x * ua[0] + c4.y * ua[1] + c4.z * ua[2] + c4.w * ua[3];
        g1[j] += c4.x * ubv[0] + c4.y * ubv[1] + c4.z * ubv[2] + c4.w * ubv[3];
      }
    }
#pragma unroll
    for (int j = 0; j < JCAP; ++j) {
      *(float2*)&Gp[wave][j][2 * lane] = make_float2(g0[j], g1[j]);
    }
  }
  __syncthreads();

  for (int i = t; i < JCAP * KD; i += 256) {
    const int j = i >> 7, k = i & 127;
    float v = Gp[0][j][k] + Gp[1][j][k] + Gp[2][j][k] + Gp[3][j][k];
    atomicAdd(&G[(size_t)(b * JCAP + j) * KD + k], v);
  }
}

// ---- K4: o2 = G2@W per (b,j); squash; write fp32 -----------------------
__global__ __launch_bounds__(256) void k_out(const float* __restrict__ G,
                                             const float* __restrict__ W,
                                             float* __restrict__ out) {
  const int b = blockIdx.x;
  const int t = threadIdx.x;
  __shared__ float o_s[JDIM];
  __shared__ float sc[JCAP];
  if (t < JDIM) {
    const int j = t >> 4;
    const float* g = G + (size_t)(b * JCAP + j) * KD;
    float acc = 0.f;
#pragma unroll 4
    for (int k = 0; k < KD; ++k) acc += g[k] * W[k * JDIM + t];
    o_s[t] = acc;
  }
  __syncthreads();
  if (t < JCAP) {
    float s2 = 0.f;
#pragma unroll
    for (int d = 0; d < DCAP; ++d) { float x = o_s[t * DCAP + d]; s2 += x * x; }
    sc[t] = s2 / ((1.f + s2) * sqrtf(s2 + EPSQ));
  }
  __syncthreads();
  if (t < JDIM) out[b * JDIM + t] = o_s[t] * sc[t >> 4];
}

extern "C" void kernel_launch(void* const* d_in, const int* in_sizes, int n_in,
                              void* d_out, int out_size, void* d_ws, size_t ws_size,
                              hipStream_t stream) {
  const float* u = (const float*)d_in[0];   // (64,2048,128) fp32
  const float* W = (const float*)d_in[1];   // (128,160) fp32
  float* out = (float*)d_out;               // (64,10,16) fp32

  float* ws = (float*)d_ws;
  float* S  = ws;                        //  8192 floats (atomic -> needs zero)
  float* G1 = ws + 8192;                 // 81920 floats (atomic -> needs zero)
  float* G2 = ws + 8192 + 81920;         // 81920 floats (atomic -> needs zero)
  float* V  = ws + 8192 + 2 * 81920;     // 81920 floats (fully overwritten)
  const size_t zero_bytes = (size_t)(8192 + 2 * 81920) * sizeof(float);
  hipMemsetAsync(d_ws, 0, zero_bytes, stream);   // S, G1, G2 only

  k_colsum<<<dim3(8, BATCH), 256, 0, stream>>>(u, S);
  k_makeV <<<BATCH, 256, 0, stream>>>(S, W, V, 1, 0.1f);
  k_route <<<dim3(8, BATCH), 256, 0, stream>>>(u, V, G1);
  k_makeV <<<BATCH, 256, 0, stream>>>(G1, W, V, 0, 1.0f);
  k_route <<<dim3(8, BATCH), 256, 0, stream>>>(u, V, G2);
  k_out   <<<BATCH, 256, 0, stream>>>(G2, W, out);
}